// Round 3
// baseline (143.737 us; speedup 1.0000x reference)
//
#include <hip/hip_runtime.h>
#include <stdint.h>

// RBF kernel regression: out = exp(-gamma*d2(Xq,Xt)) @ alpha
// out[m] = ea[m] * sum_n w[n] * 2^( S[m][n] ),  S = (2*gamma*log2e*Xq).Xt^T
// bf16 MFMA fp32-acc; w[n]=alpha[n]*exp(-g|Xt_n|^2), ea[m]=exp(-g|Xq_m|^2)

#define MM 8192
#define NN 8192
#define DD 256
#define GAMMA (1.0f/256.0f)
#define LOG2E 1.44269504088896340736f
#define SCALE_A (2.0f*GAMMA*LOG2E)
#define NEG_G_LOG2E (-GAMMA*LOG2E)

#define BM 128
#define BN 128
#define NSPLIT 16
#define NPB (NN/NSPLIT)        // 512 cols per block
#define NSTAGES ((NPB/BN)*4)   // 16 stages of BK=64

typedef __bf16 bf16x8 __attribute__((ext_vector_type(8)));
typedef float  f32x4  __attribute__((ext_vector_type(4)));

// ws: [0,4MB) A bf16 scaled row-major; [4MB,8MB) B staged [s:4][n:8192][g':8]x16B,
//     g' = g ^ (n&7) bank swizzle; [8MB,+32K) w; [+32K,+32K) ea; then part[16][8192] f32
#define A_OFF  ((size_t)0)
#define B_OFF  ((size_t)4 << 20)
#define W_OFF  ((size_t)8 << 20)
#define EA_OFF (((size_t)8 << 20) + 32768)
#define PART_OFF (((size_t)8 << 20) + 65536)

__device__ __forceinline__ unsigned short f2bf(float f) {  // RNE f32->bf16
  union { float f; uint32_t u; } x; x.f = f;
  uint32_t u = x.u;
  u += 0x7FFFu + ((u >> 16) & 1u);
  return (unsigned short)(u >> 16);
}
__device__ __forceinline__ uint32_t pack2(float a, float b) {
  return (uint32_t)f2bf(a) | ((uint32_t)f2bf(b) << 16);
}

__device__ __forceinline__ void async_ld16(void* lds, const void* g) {
  __builtin_amdgcn_global_load_lds(
      (const __attribute__((address_space(1))) uint32_t*)g,
      (__attribute__((address_space(3))) uint32_t*)lds, 16, 0, 0);
}

__global__ __launch_bounds__(256) void prep_kernel(
    const float* __restrict__ Xq, const float* __restrict__ Xt,
    const float* __restrict__ alpha,
    unsigned short* __restrict__ Aq, char* __restrict__ Bst,
    float* __restrict__ w, float* __restrict__ ea)
{
  const int lane = threadIdx.x & 63;
  const int gw = (blockIdx.x << 2) + (threadIdx.x >> 6);
  if (gw < MM) {                       // ---- A: one wave per row, coalesced
    const int row = gw;
    const float4 v = *(const float4*)(Xq + (size_t)row * DD + lane * 4);
    float ss = v.x*v.x + v.y*v.y + v.z*v.z + v.w*v.w;
#pragma unroll
    for (int off = 32; off; off >>= 1) ss += __shfl_xor(ss, off, 64);
    ushort4 p;
    p.x = f2bf(v.x * SCALE_A); p.y = f2bf(v.y * SCALE_A);
    p.z = f2bf(v.z * SCALE_A); p.w = f2bf(v.w * SCALE_A);
    *(ushort4*)(Aq + (size_t)row * DD + lane * 4) = p;
    if (lane == 0) ea[row] = __builtin_amdgcn_exp2f(NEG_G_LOG2E * ss);
  } else {                             // ---- B: one wave per 8 cols, 16B/lane stores
    const int widx = gw - MM;          // 0..1023
    const int n  = widx * 8 + (lane >> 3);
    const int gq = lane & 7;           // storage granule g'
    const int g  = gq ^ (n & 7);       // logical granule (k = s*64 + g*8 .. +8)
    float ss = 0.f;
#pragma unroll
    for (int s = 0; s < 4; ++s) {
      const float* src = Xt + (size_t)n * DD + s * 64 + g * 8;
      const float4 f0 = *(const float4*)(src);
      const float4 f1 = *(const float4*)(src + 4);
      ss += f0.x*f0.x + f0.y*f0.y + f0.z*f0.z + f0.w*f0.w
          + f1.x*f1.x + f1.y*f1.y + f1.z*f1.z + f1.w*f1.w;
      uint4 pk;
      pk.x = pack2(f0.x, f0.y); pk.y = pack2(f0.z, f0.w);
      pk.z = pack2(f1.x, f1.y); pk.w = pack2(f1.z, f1.w);
      *(uint4*)(Bst + (((size_t)(s * NN + n) * 8 + gq) << 4)) = pk;  // 1KB run/wave
    }
    ss += __shfl_xor(ss, 1, 64);       // reduce across the 8 lanes of col n
    ss += __shfl_xor(ss, 2, 64);
    ss += __shfl_xor(ss, 4, 64);
    if (gq == 0) w[n] = alpha[n] * __builtin_amdgcn_exp2f(NEG_G_LOG2E * ss);
  }
}

__global__ __launch_bounds__(256, 4) void rbf_main(
    const unsigned short* __restrict__ Aq, const char* __restrict__ Bst,
    const float* __restrict__ w, const float* __restrict__ ea,
    float* __restrict__ part)
{
  __shared__ char lds[2 * 16384];
  const int tid  = threadIdx.x;
  const int wave = tid >> 6, lane = tid & 63;
  const int quad = lane >> 4, l16 = lane & 15;

  // XCD swizzle: xcd = b&7 gets 32 consecutive my x 4 consecutive nx
  //   -> per-XCD L2 working set = 2MB A + 1MB B = 3MB <= 4MB L2
  const int b    = blockIdx.x;
  const int xcd  = b & 7, slot = b >> 3;
  const int my   = ((xcd & 1) << 5) + (slot & 31);   // 0..63
  const int nx   = ((xcd >> 1) << 2) + (slot >> 5);  // 0..15
  const int mblk   = my * BM;
  const int nbase0 = nx * NPB;

  // A fragments register-resident for full K=256
  bf16x8 afrag[2][8];
#pragma unroll
  for (int rt = 0; rt < 2; ++rt)
#pragma unroll
    for (int kc = 0; kc < 8; ++kc) {
      union { uint4 u; bf16x8 v; } cv;
      cv.u = *(const uint4*)(Aq + (size_t)(mblk + wave * 32 + rt * 16 + l16) * DD
                                 + kc * 32 + quad * 8);
      afrag[rt][kc] = cv.v;
    }

  const f32x4 fzero = {0.f, 0.f, 0.f, 0.f};
  f32x4 acc[2][8];
#pragma unroll
  for (int rt = 0; rt < 2; ++rt)
#pragma unroll
    for (int ct = 0; ct < 8; ++ct) acc[rt][ct] = fzero;
  float outacc[2][4] = {{0.f,0.f,0.f,0.f},{0.f,0.f,0.f,0.f}};

  auto issue = [&](int st) {
    const int ntile = st >> 2, s = st & 3;
    const char* g = Bst + ((size_t)(s * NN + nbase0 + ntile * BN + wave * 32) << 7)
                        + (size_t)lane * 16;
    char* l = lds + (st & 1) * 16384 + wave * 32 * 128;  // wave-uniform base
#pragma unroll
    for (int j = 0; j < 4; ++j) async_ld16(l + j * 1024, g + j * 1024);
  };

  issue(0);
  for (int st = 0; st < NSTAGES; ++st) {
    __syncthreads();
    if (st + 1 < NSTAGES) issue(st + 1);
    const char* buf = lds + (st & 1) * 16384;
#pragma unroll
    for (int kcL = 0; kcL < 2; ++kcL) {
      const int kc = (st & 3) * 2 + kcL;
#pragma unroll
      for (int ct = 0; ct < 8; ++ct) {
        const int gp = (kcL * 4 + quad) ^ (l16 & 7);   // bank swizzle: <=2-way (free)
        union { uint4 u; bf16x8 v; } cv;
        cv.u = *(const uint4*)(buf + (ct * 16 + l16) * 128 + gp * 16);
        acc[0][ct] = __builtin_amdgcn_mfma_f32_16x16x32_bf16(afrag[0][kc], cv.v, acc[0][ct], 0, 0, 0);
        acc[1][ct] = __builtin_amdgcn_mfma_f32_16x16x32_bf16(afrag[1][kc], cv.v, acc[1][ct], 0, 0, 0);
      }
    }
    if ((st & 3) == 3) {  // finished 128-col tile: C/D row=quad*4+reg, col=l16
      const int nb = nbase0 + (st >> 2) * BN;
#pragma unroll
      for (int ct = 0; ct < 8; ++ct) {
        const float wv = w[nb + ct * 16 + l16];
#pragma unroll
        for (int rt = 0; rt < 2; ++rt) {
          f32x4 a = acc[rt][ct];
          outacc[rt][0] += wv * __builtin_amdgcn_exp2f(a[0]);
          outacc[rt][1] += wv * __builtin_amdgcn_exp2f(a[1]);
          outacc[rt][2] += wv * __builtin_amdgcn_exp2f(a[2]);
          outacc[rt][3] += wv * __builtin_amdgcn_exp2f(a[3]);
          acc[rt][ct] = fzero;
        }
      }
    }
  }

  // reduce across l16, write exclusive per-block partials (no atomics)
#pragma unroll
  for (int rt = 0; rt < 2; ++rt)
#pragma unroll
    for (int i = 0; i < 4; ++i) {
      float v = outacc[rt][i];
      v += __shfl_xor(v, 1, 64);
      v += __shfl_xor(v, 2, 64);
      v += __shfl_xor(v, 4, 64);
      v += __shfl_xor(v, 8, 64);
      if (l16 == 0) {
        const int row = mblk + wave * 32 + rt * 16 + quad * 4 + i;
        part[(size_t)nx * MM + row] = ea[row] * v;
      }
    }
}

__global__ __launch_bounds__(256) void reduce_kernel(
    const float* __restrict__ part, float* __restrict__ out)
{
  const int row = blockIdx.x * 256 + threadIdx.x;
  float s = 0.f;
#pragma unroll
  for (int i = 0; i < NSPLIT; ++i) s += part[(size_t)i * MM + row];
  out[row] = s;
}

extern "C" void kernel_launch(void* const* d_in, const int* in_sizes, int n_in,
                              void* d_out, int out_size, void* d_ws, size_t ws_size,
                              hipStream_t stream) {
  const float* Xq    = (const float*)d_in[0];
  const float* Xt    = (const float*)d_in[1];
  const float* alpha = (const float*)d_in[2];
  float* out = (float*)d_out;
  char*  ws  = (char*)d_ws;

  unsigned short* Aq = (unsigned short*)(ws + A_OFF);
  char*  Bst  = ws + B_OFF;
  float* w    = (float*)(ws + W_OFF);
  float* ea   = (float*)(ws + EA_OFF);
  float* part = (float*)(ws + PART_OFF);

  hipLaunchKernelGGL(prep_kernel, dim3((MM + NN / 8) / 4), dim3(256), 0, stream,
                     Xq, Xt, alpha, Aq, Bst, w, ea);
  hipLaunchKernelGGL(rbf_main, dim3(NSPLIT * (MM / BM)), dim3(256), 0, stream,
                     Aq, Bst, w, ea, part);
  hipLaunchKernelGGL(reduce_kernel, dim3(MM / 256), dim3(256), 0, stream,
                     part, out);
}

// Round 4
// 140.682 us; speedup vs baseline: 1.0217x; 1.0217x over previous
//
#include <hip/hip_runtime.h>
#include <stdint.h>

// RBF kernel regression: out = exp(-gamma*d2(Xq,Xt)) @ alpha
// out[m] = ea[m] * sum_n w[n] * 2^( S[m][n] ),  S = (2*gamma*log2e*Xq).Xt^T
// bf16 MFMA fp32-acc; w[n]=alpha[n]*exp(-g|Xt_n|^2), ea[m]=exp(-g|Xq_m|^2)
//
// R4: time == bytes-staged/2.9TB/s (R2/R3 invariant). BM 128->256 via 512-thread
// blocks halves B staging (256->128 MB). Per-wave structure unchanged.

#define MM 8192
#define NN 8192
#define DD 256
#define GAMMA (1.0f/256.0f)
#define LOG2E 1.44269504088896340736f
#define SCALE_A (2.0f*GAMMA*LOG2E)
#define NEG_G_LOG2E (-GAMMA*LOG2E)

#define BM 256
#define BN 128
#define NSPLIT 16
#define NPB (NN/NSPLIT)        // 512 cols per block
#define NSTAGES ((NPB/BN)*4)   // 16 stages of BK=64

typedef __bf16 bf16x8 __attribute__((ext_vector_type(8)));
typedef float  f32x4  __attribute__((ext_vector_type(4)));

// ws: [0,4MB) A bf16 scaled row-major; [4MB,8MB) B staged [s:4][n:8192][g':8]x16B,
//     g' = g ^ (n&7) bank swizzle; [8MB,+32K) w; [+32K,+32K) ea; then part[16][8192] f32
#define A_OFF  ((size_t)0)
#define B_OFF  ((size_t)4 << 20)
#define W_OFF  ((size_t)8 << 20)
#define EA_OFF (((size_t)8 << 20) + 32768)
#define PART_OFF (((size_t)8 << 20) + 65536)

__device__ __forceinline__ unsigned short f2bf(float f) {  // RNE f32->bf16
  union { float f; uint32_t u; } x; x.f = f;
  uint32_t u = x.u;
  u += 0x7FFFu + ((u >> 16) & 1u);
  return (unsigned short)(u >> 16);
}
__device__ __forceinline__ uint32_t pack2(float a, float b) {
  return (uint32_t)f2bf(a) | ((uint32_t)f2bf(b) << 16);
}

__device__ __forceinline__ void async_ld16(void* lds, const void* g) {
  __builtin_amdgcn_global_load_lds(
      (const __attribute__((address_space(1))) uint32_t*)g,
      (__attribute__((address_space(3))) uint32_t*)lds, 16, 0, 0);
}

__global__ __launch_bounds__(256) void prep_kernel(
    const float* __restrict__ Xq, const float* __restrict__ Xt,
    const float* __restrict__ alpha,
    unsigned short* __restrict__ Aq, char* __restrict__ Bst,
    float* __restrict__ w, float* __restrict__ ea)
{
  const int lane = threadIdx.x & 63;
  const int gw = (blockIdx.x << 2) + (threadIdx.x >> 6);
  if (gw < MM) {                       // ---- A: one wave per row, coalesced
    const int row = gw;
    const float4 v = *(const float4*)(Xq + (size_t)row * DD + lane * 4);
    float ss = v.x*v.x + v.y*v.y + v.z*v.z + v.w*v.w;
#pragma unroll
    for (int off = 32; off; off >>= 1) ss += __shfl_xor(ss, off, 64);
    ushort4 p;
    p.x = f2bf(v.x * SCALE_A); p.y = f2bf(v.y * SCALE_A);
    p.z = f2bf(v.z * SCALE_A); p.w = f2bf(v.w * SCALE_A);
    *(ushort4*)(Aq + (size_t)row * DD + lane * 4) = p;
    if (lane == 0) ea[row] = __builtin_amdgcn_exp2f(NEG_G_LOG2E * ss);
  } else {                             // ---- B: one wave per 8 cols, 16B/lane stores
    const int widx = gw - MM;          // 0..1023
    const int n  = widx * 8 + (lane >> 3);
    const int gq = lane & 7;           // storage granule g'
    const int g  = gq ^ (n & 7);       // logical granule (k = s*64 + g*8 .. +8)
    float ss = 0.f;
#pragma unroll
    for (int s = 0; s < 4; ++s) {
      const float* src = Xt + (size_t)n * DD + s * 64 + g * 8;
      const float4 f0 = *(const float4*)(src);
      const float4 f1 = *(const float4*)(src + 4);
      ss += f0.x*f0.x + f0.y*f0.y + f0.z*f0.z + f0.w*f0.w
          + f1.x*f1.x + f1.y*f1.y + f1.z*f1.z + f1.w*f1.w;
      uint4 pk;
      pk.x = pack2(f0.x, f0.y); pk.y = pack2(f0.z, f0.w);
      pk.z = pack2(f1.x, f1.y); pk.w = pack2(f1.z, f1.w);
      *(uint4*)(Bst + (((size_t)(s * NN + n) * 8 + gq) << 4)) = pk;  // 1KB run/wave
    }
    ss += __shfl_xor(ss, 1, 64);       // reduce across the 8 lanes of col n
    ss += __shfl_xor(ss, 2, 64);
    ss += __shfl_xor(ss, 4, 64);
    if (gq == 0) w[n] = alpha[n] * __builtin_amdgcn_exp2f(NEG_G_LOG2E * ss);
  }
}

__global__ __launch_bounds__(512, 4) void rbf_main(   // 4 waves/EU = 2 blocks/CU
    const unsigned short* __restrict__ Aq, const char* __restrict__ Bst,
    const float* __restrict__ w, const float* __restrict__ ea,
    float* __restrict__ part)
{
  __shared__ char lds[2 * 16384];
  const int tid  = threadIdx.x;
  const int wave = tid >> 6, lane = tid & 63;   // 8 waves
  const int quad = lane >> 4, l16 = lane & 15;

  // XCD swizzle: 512 blocks = 32 my x 16 nx; xcd=b&7 gets 16 my x 4 nx
  //   per-XCD L2 set = 2MB A + 1MB B
  const int b    = blockIdx.x;
  const int xcd  = b & 7, slot = b >> 3;             // slot 0..63
  const int my   = ((xcd & 1) << 4) + (slot & 15);   // 0..31
  const int nx   = ((xcd >> 1) << 2) + (slot >> 4);  // 0..15
  const int mblk   = my * BM;
  const int nbase0 = nx * NPB;

  // A fragments register-resident for full K=256 (32 rows/wave, same as R3)
  bf16x8 afrag[2][8];
#pragma unroll
  for (int rt = 0; rt < 2; ++rt)
#pragma unroll
    for (int kc = 0; kc < 8; ++kc) {
      union { uint4 u; bf16x8 v; } cv;
      cv.u = *(const uint4*)(Aq + (size_t)(mblk + wave * 32 + rt * 16 + l16) * DD
                                 + kc * 32 + quad * 8);
      afrag[rt][kc] = cv.v;
    }

  const f32x4 fzero = {0.f, 0.f, 0.f, 0.f};
  f32x4 acc[2][8];
#pragma unroll
  for (int rt = 0; rt < 2; ++rt)
#pragma unroll
    for (int ct = 0; ct < 8; ++ct) acc[rt][ct] = fzero;
  float outacc[2][4] = {{0.f,0.f,0.f,0.f},{0.f,0.f,0.f,0.f}};

  auto issue = [&](int st) {           // each wave stages 16 B-rows = 2 KB
    const int ntile = st >> 2, s = st & 3;
    const char* g = Bst + ((size_t)(s * NN + nbase0 + ntile * BN + wave * 16) << 7)
                        + (size_t)lane * 16;
    char* l = lds + (st & 1) * 16384 + wave * 16 * 128;  // wave-uniform base
    async_ld16(l, g);
    async_ld16(l + 1024, g + 1024);
  };

  issue(0);
  for (int st = 0; st < NSTAGES; ++st) {
    __syncthreads();
    if (st + 1 < NSTAGES) issue(st + 1);
    const char* buf = lds + (st & 1) * 16384;
#pragma unroll
    for (int kcL = 0; kcL < 2; ++kcL) {
      const int kc = (st & 3) * 2 + kcL;
#pragma unroll
      for (int ct = 0; ct < 8; ++ct) {
        const int gp = (kcL * 4 + quad) ^ (l16 & 7);   // bank swizzle: <=2-way (free)
        union { uint4 u; bf16x8 v; } cv;
        cv.u = *(const uint4*)(buf + (ct * 16 + l16) * 128 + gp * 16);
        acc[0][ct] = __builtin_amdgcn_mfma_f32_16x16x32_bf16(afrag[0][kc], cv.v, acc[0][ct], 0, 0, 0);
        acc[1][ct] = __builtin_amdgcn_mfma_f32_16x16x32_bf16(afrag[1][kc], cv.v, acc[1][ct], 0, 0, 0);
      }
    }
    if ((st & 3) == 3) {  // finished 128-col tile: C/D row=quad*4+reg, col=l16
      const int nb = nbase0 + (st >> 2) * BN;
#pragma unroll
      for (int ct = 0; ct < 8; ++ct) {
        const float wv = w[nb + ct * 16 + l16];
#pragma unroll
        for (int rt = 0; rt < 2; ++rt) {
          f32x4 a = acc[rt][ct];
          outacc[rt][0] += wv * __builtin_amdgcn_exp2f(a[0]);
          outacc[rt][1] += wv * __builtin_amdgcn_exp2f(a[1]);
          outacc[rt][2] += wv * __builtin_amdgcn_exp2f(a[2]);
          outacc[rt][3] += wv * __builtin_amdgcn_exp2f(a[3]);
          acc[rt][ct] = fzero;
        }
      }
    }
  }

  // reduce across l16, write exclusive per-block partials (no atomics)
#pragma unroll
  for (int rt = 0; rt < 2; ++rt)
#pragma unroll
    for (int i = 0; i < 4; ++i) {
      float v = outacc[rt][i];
      v += __shfl_xor(v, 1, 64);
      v += __shfl_xor(v, 2, 64);
      v += __shfl_xor(v, 4, 64);
      v += __shfl_xor(v, 8, 64);
      if (l16 == 0) {
        const int row = mblk + wave * 32 + rt * 16 + quad * 4 + i;
        part[(size_t)nx * MM + row] = ea[row] * v;
      }
    }
}

__global__ __launch_bounds__(256) void reduce_kernel(
    const float* __restrict__ part, float* __restrict__ out)
{
  const int row = blockIdx.x * 256 + threadIdx.x;
  float s = 0.f;
#pragma unroll
  for (int i = 0; i < NSPLIT; ++i) s += part[(size_t)i * MM + row];
  out[row] = s;
}

extern "C" void kernel_launch(void* const* d_in, const int* in_sizes, int n_in,
                              void* d_out, int out_size, void* d_ws, size_t ws_size,
                              hipStream_t stream) {
  const float* Xq    = (const float*)d_in[0];
  const float* Xt    = (const float*)d_in[1];
  const float* alpha = (const float*)d_in[2];
  float* out = (float*)d_out;
  char*  ws  = (char*)d_ws;

  unsigned short* Aq = (unsigned short*)(ws + A_OFF);
  char*  Bst  = ws + B_OFF;
  float* w    = (float*)(ws + W_OFF);
  float* ea   = (float*)(ws + EA_OFF);
  float* part = (float*)(ws + PART_OFF);

  hipLaunchKernelGGL(prep_kernel, dim3((MM + NN / 8) / 4), dim3(256), 0, stream,
                     Xq, Xt, alpha, Aq, Bst, w, ea);
  hipLaunchKernelGGL(rbf_main, dim3(NSPLIT * (MM / BM)), dim3(512), 0, stream,
                     Aq, Bst, w, ea, part);
  hipLaunchKernelGGL(reduce_kernel, dim3(MM / 256), dim3(256), 0, stream,
                     part, out);
}